// Round 12
// baseline (195.122 us; speedup 1.0000x reference)
//
#include <hip/hip_runtime.h>
#include <math.h>

#define KNN 20
#define NPTS 4096
#define BATCH 8
#define P_TOT (BATCH * NPTS)       // 32768
#define QPW 8                      // queries per wave (4 half-split rounds)
#define WPB 8                      // waves per block (512 threads)
#define QPB (QPW * WPB)            // 64 queries per block
#define NBLK (P_TOT / QPB)         // 512 blocks
#define BPB (NPTS / QPB)           // 64 blocks per batch
#define BN_EPS 1e-5
#define NEG_SLOPE 0.2f

// float-offsets into ws
#define FO_CLOUD 0                 // 32768 float4 = 131072 floats
#define FO_PART  131072            // 512 x 128 block partials
#define FO_PART2 196608            // 64 x 128 stage-2 partials
#define FO_AB    655360            // 128 floats (a, shift)
#define FO_W2    655488            // 448 floats (folded W + bias)
#define FO_BIG   655936            // rawmin (2097152 f) or idx (655360 i)

// ---------- kernel 1: pack cloud as float4 (x,y,z,|p|^2) ----------
__global__ __launch_bounds__(256) void pack_kernel(const float* __restrict__ pcd,
                                                   float4* __restrict__ cloud) {
    int i = blockIdx.x * 256 + threadIdx.x;
    float x = pcd[3 * i], y = pcd[3 * i + 1], z = pcd[3 * i + 2];
    float sq = __fadd_rn(__fadd_rn(__fmul_rn(x, x), __fmul_rn(y, y)), __fmul_rn(z, z));
    cloud[i] = make_float4(x, y, z, sq);
}

// distance, bit-exact vs reference (validated R1-R11)
__device__ __forceinline__ float distf(float4 C, float qx, float qy, float qz, float qs) {
    float dot_ = __fadd_rn(__fadd_rn(__fmul_rn(qx, C.x), __fmul_rn(qy, C.y)),
                           __fmul_rn(qz, C.z));
    return fmaf(-2.0f, dot_, __fadd_rn(qs, C.w));
}

// top-2 maintenance, R4's exact select-based version (validated).
__device__ __forceinline__ void upd2(float& v1, float& v2, int& s1, int& s2, float dd, int j) {
    const bool c1 = dd < v1;
    const bool c2 = dd < v2;
    v2 = c1 ? v1 : (c2 ? dd : v2);
    s2 = c1 ? s1 : (c2 ? j : s2);
    v1 = c1 ? dd : v1;
    s1 = c1 ? j : s1;
}

// ---- half-wave (32-lane) min chains via DPP (steps 1-4) + one swizzle (xor16) ----
// (validated R9). ctrl must be a compile-time literal -> template parameter.
template <int CTRL>
__device__ __forceinline__ int dpp_mov(int v) {
    return __builtin_amdgcn_update_dpp(v, v, CTRL, 0xf, 0xf, false);
}
__device__ __forceinline__ float hmin_f(float v) {
    v = fminf(v, __int_as_float(dpp_mov<0xB1>(__float_as_int(v))));
    v = fminf(v, __int_as_float(dpp_mov<0x4E>(__float_as_int(v))));
    v = fminf(v, __int_as_float(dpp_mov<0x141>(__float_as_int(v))));
    v = fminf(v, __int_as_float(dpp_mov<0x140>(__float_as_int(v))));
    v = fminf(v, __int_as_float(__builtin_amdgcn_ds_swizzle(__float_as_int(v), 0x401F)));
    return v;
}
__device__ __forceinline__ int hmin_i(int v) {
    v = min(v, dpp_mov<0xB1>(v));
    v = min(v, dpp_mov<0x4E>(v));
    v = min(v, dpp_mov<0x141>(v));
    v = min(v, dpp_mov<0x140>(v));
    v = min(v, __builtin_amdgcn_ds_swizzle(v, 0x401F));
    return v;
}

// full recompute of group G's top-2 from LDS, excluding extracted slots.
// Separated from the promote path so it can sit under a wave-uniform
// __ballot guard (scalar s_cbranch skip when no lane needs it).
template <int G>
__device__ __forceinline__ void recomp(float (&gv1)[8], float (&gv2)[8],
                                       int (&gs1)[8], int (&gs2)[8],
                                       unsigned long long mk0, unsigned long long mk1,
                                       const float4* cl, int sub,
                                       float qx, float qy, float qz, float qs) {
    const unsigned long long mw = (G < 4) ? mk0 : mk1;   // compile-time select
    float w1 = INFINITY, w2 = INFINITY; int t1 = 0, t2 = 0;
#pragma unroll
    for (int e = 0; e < 16; ++e) {
        const int j = G * 16 + e;                        // compile-time slot
        const float4 C = cl[j * 32 + sub];
        float dd = distf(C, qx, qy, qz, qs);
        if ((mw >> ((G & 3) * 16 + e)) & 1ull) dd = INFINITY;  // static bit
        upd2(w1, w2, t1, t2, dd, j);
    }
    gv1[G] = w1; gv2[G] = w2; gs1[G] = t1; gs2[G] = t2;
}

// promote-only (cheap, ~8 instrs) -- sets need=true when the group is exhausted
#define PROMOTE_CASE(G, OWN, NEED) \
    case G: if (OWN) { \
        if (gv2[G] < INFINITY) { gv1[G] = gv2[G]; gs1[G] = gs2[G]; gv2[G] = INFINITY; } \
        else NEED = true; \
    } break;

#define RECOMP_CASE(G, NEED) \
    case G: if (NEED) recomp<G>(gv1, gv2, gs1, gs2, mk0, mk1, cl, sub, qx, qy, qz, qs); break;

// ---------- kernel 2: fused kNN, half-wave split (R9 geometry, guarded RECOMP) ----------
template <bool FAST>
__global__ __attribute__((amdgpu_flat_work_group_size(512, 512), amdgpu_waves_per_eu(4)))
void knn_kernel(const float4* __restrict__ cloud,
                const float* __restrict__ W,
                const float* __restrict__ bias,
                float* __restrict__ partials,
                float* __restrict__ rawmax,
                float* __restrict__ rawmin,
                int* __restrict__ idxo) {
    __shared__ float4 cl[NPTS];    // 64 KB
    const int t = threadIdx.x;
    const int wave = t >> 6, lane = t & 63;
    const int sub = lane & 31;
    const int half = lane >> 5;
    const int bidx = blockIdx.x;
    const int batch = bidx / BPB;
    const int gbase = batch * NPTS;

#pragma unroll
    for (int it = 0; it < NPTS / 512; ++it)
        cl[it * 512 + t] = cloud[gbase + it * 512 + t];
    __syncthreads();

    // per-lane (=channel) folded MLP: raw = qoff + wd0*Cx + wd1*Cy + wd2*Cz
    const float wc3 = W[192 + lane], wc4 = W[256 + lane], wc5 = W[320 + lane];
    const float wd0 = W[lane] - wc3, wd1 = W[64 + lane] - wc4, wd2 = W[128 + lane] - wc5;
    const float bb = bias[lane];
    float se = 0.f, sqs = 0.f;

#pragma unroll 1
    for (int r = 0; r < QPW / 2; ++r) {
        const int qA = (bidx % BPB) * QPB + wave * QPW + r * 2;   // in-batch ids
        const int gqA = gbase + qA;
        const float4 QA4 = cl[qA];
        const float4 QB4 = cl[qA + 1];
        // my half's query coords
        const float qx = half ? QB4.x : QA4.x;
        const float qy = half ? QB4.y : QA4.y;
        const float qz = half ? QB4.z : QA4.z;
        const float qs = half ? QB4.w : QA4.w;
        // channel-phase offsets for BOTH queries (lane = channel)
        const float qoffA = fmaf(wc3, QA4.x, fmaf(wc4, QA4.y, fmaf(wc5, QA4.z, bb)));
        const float qoffB = fmaf(wc3, QB4.x, fmaf(wc4, QB4.y, fmaf(wc5, QB4.z, bb)));

        // ---- distance pass: 128 candidates per lane, 8 groups x 16, top-2/group ----
        float gv1[8], gv2[8];
        int gs1[8], gs2[8];
#pragma unroll
        for (int g = 0; g < 8; ++g) { gv1[g] = INFINITY; gv2[g] = INFINITY; gs1[g] = 0; gs2[g] = 0; }
#pragma unroll
        for (int g = 0; g < 8; ++g) {
#pragma unroll
            for (int h2 = 0; h2 < 2; ++h2) {
#pragma unroll
                for (int e = 0; e < 8; ++e) {
                    const int j = g * 16 + h2 * 8 + e;       // compile-time slot, ascending
                    const float4 C = cl[j * 32 + sub];       // halves share addr: broadcast
                    const float dd = distf(C, qx, qy, qz, qs);
                    upd2(gv1[g], gv2[g], gs1[g], gs2[g], dd, j);
                }
                __builtin_amdgcn_sched_barrier(0);           // cap live loads at 8
            }
        }
        // initial per-lane tournament (ties -> lowest g -> lowest index)
        float dmin = gv1[0]; int bsj = gs1[0];
#pragma unroll
        for (int g = 1; g < 8; ++g) if (gv1[g] < dmin) { dmin = gv1[g]; bsj = gs1[g]; }
        int mmin = (bsj << 5) | sub;

        unsigned long long mk0 = 0ull, mk1 = 0ull;
        float hmaxA = -INFINITY, hminA = INFINITY;
        float hmaxB = -INFINITY, hminB = INFINITY;

#pragma unroll 1
        for (int p = 0; p < KNN; ++p) {
            // per-half min by (distance, index) -- branchless, ties -> lowest index
            const float gmin = hmin_f(dmin);
            const int cand = (dmin == gmin) ? mmin : 0x7FFFFFFF;
            const int win = hmin_i(cand);                    // uniform within each half

            if (!FAST) { if (sub == 0) idxo[(gbase + qA + half) * KNN + p] = win; }

            // scalar winners for the wave-wide channel phase
            const int winA_s = __builtin_amdgcn_readlane(win, 0);
            const int winB_s = __builtin_amdgcn_readlane(win, 32);
            const float4 CA = cl[winA_s];
            const float4 CB = cl[winB_s];
            const float rawA = fmaf(wd0, CA.x, fmaf(wd1, CA.y, fmaf(wd2, CA.z, qoffA)));
            const float rawB = fmaf(wd0, CB.x, fmaf(wd1, CB.y, fmaf(wd2, CB.z, qoffB)));
            se += rawA; sqs = fmaf(rawA, rawA, sqs);
            hmaxA = fmaxf(hmaxA, rawA); hminA = fminf(hminA, rawA);
            se += rawB; sqs = fmaf(rawB, rawB, sqs);
            hmaxB = fmaxf(hmaxB, rawB); hminB = fminf(hminB, rawB);

            if (p < KNN - 1) {
                const bool ownA = (half == 0) && ((winA_s & 31) == sub);
                const bool ownB = (half == 1) && ((winB_s & 31) == sub);
                const int slotA = winA_s >> 5;               // scalar, [0,128)
                const int slotB = winB_s >> 5;

                // mask update (R4 order: record BEFORE promote/recomp)
                {
                    const unsigned long long bA = 1ull << (slotA & 63);
                    const unsigned long long bB = 1ull << (slotB & 63);
                    if (ownA) { if (slotA < 64) mk0 |= bA; else mk1 |= bA; }  // slotA scalar: branch is scalar
                    if (ownB) { if (slotB < 64) mk0 |= bB; else mk1 |= bB; }
                }

                // cheap promote-only switches (scalar-dispatched)
                bool needA = false, needB = false;
                switch (slotA >> 4) {
                    PROMOTE_CASE(0, ownA, needA) PROMOTE_CASE(1, ownA, needA)
                    PROMOTE_CASE(2, ownA, needA) PROMOTE_CASE(3, ownA, needA)
                    PROMOTE_CASE(4, ownA, needA) PROMOTE_CASE(5, ownA, needA)
                    PROMOTE_CASE(6, ownA, needA) PROMOTE_CASE(7, ownA, needA)
                }
                switch (slotB >> 4) {
                    PROMOTE_CASE(0, ownB, needB) PROMOTE_CASE(1, ownB, needB)
                    PROMOTE_CASE(2, ownB, needB) PROMOTE_CASE(3, ownB, needB)
                    PROMOTE_CASE(4, ownB, needB) PROMOTE_CASE(5, ownB, needB)
                    PROMOTE_CASE(6, ownB, needB) PROMOTE_CASE(7, ownB, needB)
                }

                // rare full-recompute: wave-uniform ballot guard guarantees a
                // scalar s_cbranch skip (~95% of picks) regardless of
                // if-conversion heuristics on the divergent inner guard.
                if (__ballot(needA) != 0ull) {
                    switch (slotA >> 4) {
                        RECOMP_CASE(0, needA) RECOMP_CASE(1, needA)
                        RECOMP_CASE(2, needA) RECOMP_CASE(3, needA)
                        RECOMP_CASE(4, needA) RECOMP_CASE(5, needA)
                        RECOMP_CASE(6, needA) RECOMP_CASE(7, needA)
                    }
                }
                if (__ballot(needB) != 0ull) {
                    switch (slotB >> 4) {
                        RECOMP_CASE(0, needB) RECOMP_CASE(1, needB)
                        RECOMP_CASE(2, needB) RECOMP_CASE(3, needB)
                        RECOMP_CASE(4, needB) RECOMP_CASE(5, needB)
                        RECOMP_CASE(6, needB) RECOMP_CASE(7, needB)
                    }
                }

                // rebuild per-lane tournament (idempotent for non-owners)
                float nv = gv1[0]; int ns = gs1[0];
#pragma unroll
                for (int g = 1; g < 8; ++g) if (gv1[g] < nv) { nv = gv1[g]; ns = gs1[g]; }
                dmin = nv; mmin = (ns << 5) | sub;
            }
        }

        if (FAST) {
            rawmax[gqA * 64 + lane] = hmaxA;
            rawmin[gqA * 64 + lane] = hminA;
            rawmax[(gqA + 1) * 64 + lane] = hmaxB;
            rawmin[(gqA + 1) * 64 + lane] = hminB;
        }
    }

    // ---- cross-wave stats reduce (reuse cl LDS) ----
    __syncthreads();
    float* sred = (float*)cl;
    sred[wave * 128 + lane] = se;
    sred[wave * 128 + 64 + lane] = sqs;
    __syncthreads();
    if (t < 128) {
        float s = 0.f;
#pragma unroll
        for (int w = 0; w < WPB; ++w) s += sred[w * 128 + t];
        partials[bidx * 128 + t] = s;
    }
}

// ---------- kernel 3a: reduce 512 block-partials -> 64 ----------
__global__ __launch_bounds__(128) void finA_kernel(const float* __restrict__ partials,
                                                   float* __restrict__ part2) {
    const int b = blockIdx.x, t = threadIdx.x;   // 64 blocks x 128 threads
    float s = 0.f;
#pragma unroll
    for (int i = 0; i < 8; ++i) s += partials[(b * 8 + i) * 128 + t];
    part2[b * 128 + t] = s;
}

// ---------- kernel 3b: finalize BN, fold affine ----------
__global__ __launch_bounds__(64) void finB_kernel(const float* __restrict__ part2,
                                                  const float* __restrict__ W,
                                                  const float* __restrict__ bias,
                                                  const float* __restrict__ gamma,
                                                  const float* __restrict__ beta,
                                                  float* __restrict__ ab,
                                                  float* __restrict__ w2) {
    const int c = threadIdx.x;   // 64 threads
    double s0 = 0.0, s1 = 0.0, q0 = 0.0, q1 = 0.0;
    for (int i = 0; i < 64; i += 2) {
        s0 += (double)part2[i * 128 + c];
        q0 += (double)part2[i * 128 + 64 + c];
        s1 += (double)part2[(i + 1) * 128 + c];
        q1 += (double)part2[(i + 1) * 128 + 64 + c];
    }
    const double cnt = (double)P_TOT * KNN;
    double mean = (s0 + s1) / cnt;
    double var = (q0 + q1) / cnt - mean * mean;
    double a = (double)gamma[c] / sqrt(var + BN_EPS);
    float af = (float)a;
    float sh = (float)((double)beta[c] - mean * a);
    ab[c] = af;
    ab[64 + c] = sh;
#pragma unroll
    for (int f = 0; f < 6; ++f) w2[f * 64 + c] = W[f * 64 + c] * af;
    w2[384 + c] = fmaf(bias[c], af, sh);
}

// ---------- kernel 4a (fast): elementwise BN+LeakyReLU on raw max/min ----------
__global__ __launch_bounds__(256) void final_kernel(const float* __restrict__ ab,
                                                    const float* __restrict__ rawmin,
                                                    float* __restrict__ out) {
    int i = blockIdx.x * 256 + threadIdx.x;
    int c = i & 63;
    float a = ab[c], sh = ab[64 + c];
    float va = fmaf(a, out[i], sh);       // out currently holds rawmax
    float vb = fmaf(a, rawmin[i], sh);
    va = va >= 0.f ? va : NEG_SLOPE * va;
    vb = vb >= 0.f ? vb : NEG_SLOPE * vb;
    out[i] = fmaxf(va, vb);               // monotone: covers a>=0 and a<0
}

// ---------- kernel 4b (fallback): gather + folded MLP + maxpool ----------
__global__ __launch_bounds__(256) void out_kernel(const float4* __restrict__ cloud,
                                                  const int* __restrict__ idxo,
                                                  const float* __restrict__ w2,
                                                  float* __restrict__ out) {
    const int t = threadIdx.x, c = t & 63;
    const int gp = blockIdx.x * 4 + (t >> 6);
    const int gb = gp & ~(NPTS - 1);
    const float wc0 = w2[c], wc1 = w2[64 + c], wc2 = w2[128 + c];
    const float wc3 = w2[192 + c], wc4 = w2[256 + c], wc5 = w2[320 + c];
    const float bc = w2[384 + c];
    const float4 Q = cloud[gp];
    float vmax = -INFINITY;
    for (int k = 0; k < KNN; ++k) {
        const int m = idxo[gp * KNN + k];
        const float4 C = cloud[gb + m];
        float h = bc;
        h = fmaf(wc0, C.x, h);
        h = fmaf(wc1, C.y, h);
        h = fmaf(wc2, C.z, h);
        h = fmaf(wc3, Q.x - C.x, h);
        h = fmaf(wc4, Q.y - C.y, h);
        h = fmaf(wc5, Q.z - C.z, h);
        h = h >= 0.f ? h : NEG_SLOPE * h;
        vmax = fmaxf(vmax, h);
    }
    out[gp * 64 + c] = vmax;
}

extern "C" void kernel_launch(void* const* d_in, const int* in_sizes, int n_in,
                              void* d_out, int out_size, void* d_ws, size_t ws_size,
                              hipStream_t stream) {
    const float* pcd   = (const float*)d_in[0];
    const float* W     = (const float*)d_in[1];
    const float* bias  = (const float*)d_in[2];
    const float* gamma = (const float*)d_in[3];
    const float* beta  = (const float*)d_in[4];

    float* wsf = (float*)d_ws;
    float4* cloud   = (float4*)(wsf + FO_CLOUD);
    float* partials = wsf + FO_PART;
    float* part2    = wsf + FO_PART2;
    float* ab       = wsf + FO_AB;
    float* w2       = wsf + FO_W2;
    float* big      = wsf + FO_BIG;
    float* out      = (float*)d_out;

    const size_t need_fast = (size_t)FO_BIG * 4 + (size_t)P_TOT * 64 * 4 + 1024;
    const bool fast = ws_size >= need_fast;

    pack_kernel<<<P_TOT / 256, 256, 0, stream>>>(pcd, cloud);
    if (fast) {
        knn_kernel<true><<<NBLK, 512, 0, stream>>>(cloud, W, bias, partials, out, big, nullptr);
        finA_kernel<<<64, 128, 0, stream>>>(partials, part2);
        finB_kernel<<<1, 64, 0, stream>>>(part2, W, bias, gamma, beta, ab, w2);
        final_kernel<<<(P_TOT * 64) / 256, 256, 0, stream>>>(ab, big, out);
    } else {
        knn_kernel<false><<<NBLK, 512, 0, stream>>>(cloud, W, bias, partials, nullptr, nullptr, (int*)big);
        finA_kernel<<<64, 128, 0, stream>>>(partials, part2);
        finB_kernel<<<1, 64, 0, stream>>>(part2, W, bias, gamma, beta, ab, w2);
        out_kernel<<<P_TOT / 4, 256, 0, stream>>>(cloud, (int*)big, w2, out);
    }
}

// Round 13
// 179.760 us; speedup vs baseline: 1.0855x; 1.0855x over previous
//
#include <hip/hip_runtime.h>
#include <math.h>

#define KNN 20
#define NPTS 4096
#define BATCH 8
#define P_TOT (BATCH * NPTS)       // 32768
#define QPW 8                      // queries per wave (4 half-split rounds)
#define WPB 8                      // waves per block (512 threads)
#define QPB (QPW * WPB)            // 64 queries per block
#define NBLK (P_TOT / QPB)         // 512 blocks
#define BPB (NPTS / QPB)           // 64 blocks per batch
#define BN_EPS 1e-5
#define NEG_SLOPE 0.2f

// float-offsets into ws
#define FO_CLOUD 0                 // 32768 float4 = 131072 floats
#define FO_PART  131072            // 512 x 128 block partials
#define FO_PART2 196608            // 64 x 128 stage-2 partials
#define FO_AB    655360            // 128 floats (a, shift)
#define FO_W2    655488            // 448 floats (folded W + bias)
#define FO_BIG   655936            // rawmin (2097152 f) or idx (655360 i)

// ---------- kernel 1: pack cloud as float4 (x,y,z,|p|^2) ----------
__global__ __launch_bounds__(256) void pack_kernel(const float* __restrict__ pcd,
                                                   float4* __restrict__ cloud) {
    int i = blockIdx.x * 256 + threadIdx.x;
    float x = pcd[3 * i], y = pcd[3 * i + 1], z = pcd[3 * i + 2];
    float sq = __fadd_rn(__fadd_rn(__fmul_rn(x, x), __fmul_rn(y, y)), __fmul_rn(z, z));
    cloud[i] = make_float4(x, y, z, sq);
}

// distance, bit-exact vs reference (validated R1-R12)
__device__ __forceinline__ float distf(float4 C, float qx, float qy, float qz, float qs) {
    float dot_ = __fadd_rn(__fadd_rn(__fmul_rn(qx, C.x), __fmul_rn(qy, C.y)),
                           __fmul_rn(qz, C.z));
    return fmaf(-2.0f, dot_, __fadd_rn(qs, C.w));
}

// top-2 maintenance. Values: v1'=min(dd,v1), v2'=med3(dd,v1,v2) (middle of the
// three = correct new second-smallest; INF-init safe: med3(dd,v1,INF)=max(dd,v1),
// med3(dd,INF,INF)=INF). Indices: same strict-< cmps as R4 (ties -> lowest j).
__device__ __forceinline__ void upd2(float& v1, float& v2, int& s1, int& s2, float dd, int j) {
    const bool c1 = dd < v1;
    const bool c2 = dd < v2;
    const float nv2 = __builtin_amdgcn_fmed3f(dd, v1, v2);
    s2 = c1 ? s1 : (c2 ? j : s2);
    s1 = c1 ? j : s1;
    v1 = fminf(dd, v1);
    v2 = nv2;
}

// ---- half-wave (32-lane) min chains via DPP (steps 1-4) + one swizzle (xor16) ----
// (validated R9). ctrl must be a compile-time literal -> template parameter.
template <int CTRL>
__device__ __forceinline__ int dpp_mov(int v) {
    return __builtin_amdgcn_update_dpp(v, v, CTRL, 0xf, 0xf, false);
}
__device__ __forceinline__ float hmin_f(float v) {
    v = fminf(v, __int_as_float(dpp_mov<0xB1>(__float_as_int(v))));
    v = fminf(v, __int_as_float(dpp_mov<0x4E>(__float_as_int(v))));
    v = fminf(v, __int_as_float(dpp_mov<0x141>(__float_as_int(v))));
    v = fminf(v, __int_as_float(dpp_mov<0x140>(__float_as_int(v))));
    v = fminf(v, __int_as_float(__builtin_amdgcn_ds_swizzle(__float_as_int(v), 0x401F)));
    return v;
}
__device__ __forceinline__ int hmin_i(int v) {
    v = min(v, dpp_mov<0xB1>(v));
    v = min(v, dpp_mov<0x4E>(v));
    v = min(v, dpp_mov<0x141>(v));
    v = min(v, dpp_mov<0x140>(v));
    v = min(v, __builtin_amdgcn_ds_swizzle(v, 0x401F));
    return v;
}

// promote group G's second to first, or mask-based recompute of top-2 from LDS.
// 8 groups x 16 slots per lane; slots 0-63 tracked in mk0, 64-127 in mk1.
template <int G>
__device__ __forceinline__ void prom(float (&gv1)[8], float (&gv2)[8],
                                     int (&gs1)[8], int (&gs2)[8],
                                     unsigned long long mk0, unsigned long long mk1,
                                     const float4* cl, int sub,
                                     float qx, float qy, float qz, float qs) {
    if (gv2[G] < INFINITY) {
        gv1[G] = gv2[G]; gs1[G] = gs2[G]; gv2[G] = INFINITY;
    } else {
        const unsigned long long mw = (G < 4) ? mk0 : mk1;   // compile-time select
        float w1 = INFINITY, w2 = INFINITY; int t1 = 0, t2 = 0;
#pragma unroll
        for (int e = 0; e < 16; ++e) {
            const int j = G * 16 + e;                        // compile-time slot
            const float4 C = cl[j * 32 + sub];
            float dd = distf(C, qx, qy, qz, qs);
            if ((mw >> ((G & 3) * 16 + e)) & 1ull) dd = INFINITY;  // static bit
            upd2(w1, w2, t1, t2, dd, j);
        }
        gv1[G] = w1; gv2[G] = w2; gs1[G] = t1; gs2[G] = t2;
    }
}

// repair one half's owner lane; win_s is a scalar (readlane result)
__device__ __forceinline__ void repair_half(int win_s, bool own,
                                            float (&gv1)[8], float (&gv2)[8],
                                            int (&gs1)[8], int (&gs2)[8],
                                            unsigned long long& mk0, unsigned long long& mk1,
                                            const float4* cl, int sub,
                                            float qx, float qy, float qz, float qs) {
    const int slot_s = win_s >> 5;                           // scalar, [0,128)
    const unsigned long long b = 1ull << (slot_s & 63);      // scalar shift
    const unsigned long long blo = (slot_s < 64) ? b : 0ull;
    const unsigned long long bhi = (slot_s < 64) ? 0ull : b;
    if (own) { mk0 |= blo; mk1 |= bhi; }                     // record BEFORE prom (R4 order)
    switch (slot_s >> 4) {                                   // scalar branches, 8 cases
        case 0: if (own) prom<0>(gv1, gv2, gs1, gs2, mk0, mk1, cl, sub, qx, qy, qz, qs); break;
        case 1: if (own) prom<1>(gv1, gv2, gs1, gs2, mk0, mk1, cl, sub, qx, qy, qz, qs); break;
        case 2: if (own) prom<2>(gv1, gv2, gs1, gs2, mk0, mk1, cl, sub, qx, qy, qz, qs); break;
        case 3: if (own) prom<3>(gv1, gv2, gs1, gs2, mk0, mk1, cl, sub, qx, qy, qz, qs); break;
        case 4: if (own) prom<4>(gv1, gv2, gs1, gs2, mk0, mk1, cl, sub, qx, qy, qz, qs); break;
        case 5: if (own) prom<5>(gv1, gv2, gs1, gs2, mk0, mk1, cl, sub, qx, qy, qz, qs); break;
        case 6: if (own) prom<6>(gv1, gv2, gs1, gs2, mk0, mk1, cl, sub, qx, qy, qz, qs); break;
        default: if (own) prom<7>(gv1, gv2, gs1, gs2, mk0, mk1, cl, sub, qx, qy, qz, qs); break;
    }
}

// ---------- kernel 2: fused kNN, half-wave split (R9 base + scalar fast path) ----------
template <bool FAST>
__global__ __attribute__((amdgpu_flat_work_group_size(512, 512), amdgpu_waves_per_eu(4)))
void knn_kernel(const float4* __restrict__ cloud,
                const float* __restrict__ W,
                const float* __restrict__ bias,
                float* __restrict__ partials,
                float* __restrict__ rawmax,
                float* __restrict__ rawmin,
                int* __restrict__ idxo) {
    __shared__ float4 cl[NPTS];    // 64 KB
    const int t = threadIdx.x;
    const int wave = t >> 6, lane = t & 63;
    const int sub = lane & 31;
    const int half = lane >> 5;
    const int bidx = blockIdx.x;
    const int batch = bidx / BPB;
    const int gbase = batch * NPTS;

#pragma unroll
    for (int it = 0; it < NPTS / 512; ++it)
        cl[it * 512 + t] = cloud[gbase + it * 512 + t];
    __syncthreads();

    // per-lane (=channel) folded MLP: raw = qoff + wd0*Cx + wd1*Cy + wd2*Cz
    const float wc3 = W[192 + lane], wc4 = W[256 + lane], wc5 = W[320 + lane];
    const float wd0 = W[lane] - wc3, wd1 = W[64 + lane] - wc4, wd2 = W[128 + lane] - wc5;
    const float bb = bias[lane];
    float se = 0.f, sqs = 0.f;

#pragma unroll 1
    for (int r = 0; r < QPW / 2; ++r) {
        const int qA = (bidx % BPB) * QPB + wave * QPW + r * 2;   // in-batch ids
        const int gqA = gbase + qA;
        const float4 QA4 = cl[qA];
        const float4 QB4 = cl[qA + 1];
        // my half's query coords
        const float qx = half ? QB4.x : QA4.x;
        const float qy = half ? QB4.y : QA4.y;
        const float qz = half ? QB4.z : QA4.z;
        const float qs = half ? QB4.w : QA4.w;
        // channel-phase offsets for BOTH queries (lane = channel)
        const float qoffA = fmaf(wc3, QA4.x, fmaf(wc4, QA4.y, fmaf(wc5, QA4.z, bb)));
        const float qoffB = fmaf(wc3, QB4.x, fmaf(wc4, QB4.y, fmaf(wc5, QB4.z, bb)));

        // ---- distance pass: 128 candidates per lane, 8 groups x 16, top-2/group ----
        float gv1[8], gv2[8];
        int gs1[8], gs2[8];
#pragma unroll
        for (int g = 0; g < 8; ++g) { gv1[g] = INFINITY; gv2[g] = INFINITY; gs1[g] = 0; gs2[g] = 0; }
#pragma unroll
        for (int g = 0; g < 8; ++g) {
#pragma unroll
            for (int h2 = 0; h2 < 2; ++h2) {
#pragma unroll
                for (int e = 0; e < 8; ++e) {
                    const int j = g * 16 + h2 * 8 + e;       // compile-time slot, ascending
                    const float4 C = cl[j * 32 + sub];       // halves share addr: broadcast
                    const float dd = distf(C, qx, qy, qz, qs);
                    upd2(gv1[g], gv2[g], gs1[g], gs2[g], dd, j);
                }
                __builtin_amdgcn_sched_barrier(0);           // cap live loads at 8
            }
        }
        // initial per-lane tournament (ties -> lowest g -> lowest index)
        float dmin = gv1[0]; int bsj = gs1[0];
#pragma unroll
        for (int g = 1; g < 8; ++g) if (gv1[g] < dmin) { dmin = gv1[g]; bsj = gs1[g]; }
        int mmin = (bsj << 5) | sub;

        unsigned long long mk0 = 0ull, mk1 = 0ull;
        float hmaxA = -INFINITY, hminA = INFINITY;
        float hmaxB = -INFINITY, hminB = INFINITY;

#pragma unroll 1
        for (int p = 0; p < KNN; ++p) {
            // per-half value min (5-step DPP/swizzle chain)
            const float gmin = hmin_f(dmin);
            // who achieved it? (SGPR mask -> scalar control flow)
            const unsigned long long bal = __ballot(dmin == gmin);
            const unsigned long long balA = bal & 0xFFFFFFFFull;
            const unsigned long long balB = bal >> 32;
            int winA_s, winB_s;
            if (__builtin_expect((__builtin_popcountll(balA) == 1) &
                                 (__builtin_popcountll(balB) == 1), 1)) {
                // unique winner per half (~99.9%): skip the whole index chain
                winA_s = __builtin_amdgcn_readlane(mmin, (int)__builtin_ctzll(balA));
                winB_s = __builtin_amdgcn_readlane(mmin, 32 + (int)__builtin_ctzll(balB));
            } else {
                // exact distance tie: R9's branchless (d, idx) chain, ties -> lowest index
                const int cand = (dmin == gmin) ? mmin : 0x7FFFFFFF;
                const int win = hmin_i(cand);
                winA_s = __builtin_amdgcn_readlane(win, 0);
                winB_s = __builtin_amdgcn_readlane(win, 32);
            }

            if (!FAST) { if (sub == 0) idxo[(gbase + qA + half) * KNN + p] = half ? winB_s : winA_s; }

            // wave-wide channel phase (lane = channel), uniform broadcast
            const float4 CA = cl[winA_s];
            const float4 CB = cl[winB_s];
            const float rawA = fmaf(wd0, CA.x, fmaf(wd1, CA.y, fmaf(wd2, CA.z, qoffA)));
            const float rawB = fmaf(wd0, CB.x, fmaf(wd1, CB.y, fmaf(wd2, CB.z, qoffB)));
            se += rawA; sqs = fmaf(rawA, rawA, sqs);
            hmaxA = fmaxf(hmaxA, rawA); hminA = fminf(hminA, rawA);
            se += rawB; sqs = fmaf(rawB, rawB, sqs);
            hmaxB = fmaxf(hmaxB, rawB); hminB = fminf(hminB, rawB);

            if (p < KNN - 1) {
                const bool ownA = (half == 0) && ((winA_s & 31) == sub);
                const bool ownB = (half == 1) && ((winB_s & 31) == sub);
                repair_half(winA_s, ownA, gv1, gv2, gs1, gs2, mk0, mk1, cl, sub, qx, qy, qz, qs);
                repair_half(winB_s, ownB, gv1, gv2, gs1, gs2, mk0, mk1, cl, sub, qx, qy, qz, qs);
                // rebuild per-lane tournament (idempotent for non-owners)
                float nv = gv1[0]; int ns = gs1[0];
#pragma unroll
                for (int g = 1; g < 8; ++g) if (gv1[g] < nv) { nv = gv1[g]; ns = gs1[g]; }
                dmin = nv; mmin = (ns << 5) | sub;
            }
        }

        if (FAST) {
            rawmax[gqA * 64 + lane] = hmaxA;
            rawmin[gqA * 64 + lane] = hminA;
            rawmax[(gqA + 1) * 64 + lane] = hmaxB;
            rawmin[(gqA + 1) * 64 + lane] = hminB;
        }
    }

    // ---- cross-wave stats reduce (reuse cl LDS) ----
    __syncthreads();
    float* sred = (float*)cl;
    sred[wave * 128 + lane] = se;
    sred[wave * 128 + 64 + lane] = sqs;
    __syncthreads();
    if (t < 128) {
        float s = 0.f;
#pragma unroll
        for (int w = 0; w < WPB; ++w) s += sred[w * 128 + t];
        partials[bidx * 128 + t] = s;
    }
}

// ---------- kernel 3a: reduce 512 block-partials -> 64 ----------
__global__ __launch_bounds__(128) void finA_kernel(const float* __restrict__ partials,
                                                   float* __restrict__ part2) {
    const int b = blockIdx.x, t = threadIdx.x;   // 64 blocks x 128 threads
    float s = 0.f;
#pragma unroll
    for (int i = 0; i < 8; ++i) s += partials[(b * 8 + i) * 128 + t];
    part2[b * 128 + t] = s;
}

// ---------- kernel 3b: finalize BN, fold affine ----------
__global__ __launch_bounds__(64) void finB_kernel(const float* __restrict__ part2,
                                                  const float* __restrict__ W,
                                                  const float* __restrict__ bias,
                                                  const float* __restrict__ gamma,
                                                  const float* __restrict__ beta,
                                                  float* __restrict__ ab,
                                                  float* __restrict__ w2) {
    const int c = threadIdx.x;   // 64 threads
    double s0 = 0.0, s1 = 0.0, q0 = 0.0, q1 = 0.0;
    for (int i = 0; i < 64; i += 2) {
        s0 += (double)part2[i * 128 + c];
        q0 += (double)part2[i * 128 + 64 + c];
        s1 += (double)part2[(i + 1) * 128 + c];
        q1 += (double)part2[(i + 1) * 128 + 64 + c];
    }
    const double cnt = (double)P_TOT * KNN;
    double mean = (s0 + s1) / cnt;
    double var = (q0 + q1) / cnt - mean * mean;
    double a = (double)gamma[c] / sqrt(var + BN_EPS);
    float af = (float)a;
    float sh = (float)((double)beta[c] - mean * a);
    ab[c] = af;
    ab[64 + c] = sh;
#pragma unroll
    for (int f = 0; f < 6; ++f) w2[f * 64 + c] = W[f * 64 + c] * af;
    w2[384 + c] = fmaf(bias[c], af, sh);
}

// ---------- kernel 4a (fast): elementwise BN+LeakyReLU on raw max/min ----------
__global__ __launch_bounds__(256) void final_kernel(const float* __restrict__ ab,
                                                    const float* __restrict__ rawmin,
                                                    float* __restrict__ out) {
    int i = blockIdx.x * 256 + threadIdx.x;
    int c = i & 63;
    float a = ab[c], sh = ab[64 + c];
    float va = fmaf(a, out[i], sh);       // out currently holds rawmax
    float vb = fmaf(a, rawmin[i], sh);
    va = va >= 0.f ? va : NEG_SLOPE * va;
    vb = vb >= 0.f ? vb : NEG_SLOPE * vb;
    out[i] = fmaxf(va, vb);               // monotone: covers a>=0 and a<0
}

// ---------- kernel 4b (fallback): gather + folded MLP + maxpool ----------
__global__ __launch_bounds__(256) void out_kernel(const float4* __restrict__ cloud,
                                                  const int* __restrict__ idxo,
                                                  const float* __restrict__ w2,
                                                  float* __restrict__ out) {
    const int t = threadIdx.x, c = t & 63;
    const int gp = blockIdx.x * 4 + (t >> 6);
    const int gb = gp & ~(NPTS - 1);
    const float wc0 = w2[c], wc1 = w2[64 + c], wc2 = w2[128 + c];
    const float wc3 = w2[192 + c], wc4 = w2[256 + c], wc5 = w2[320 + c];
    const float bc = w2[384 + c];
    const float4 Q = cloud[gp];
    float vmax = -INFINITY;
    for (int k = 0; k < KNN; ++k) {
        const int m = idxo[gp * KNN + k];
        const float4 C = cloud[gb + m];
        float h = bc;
        h = fmaf(wc0, C.x, h);
        h = fmaf(wc1, C.y, h);
        h = fmaf(wc2, C.z, h);
        h = fmaf(wc3, Q.x - C.x, h);
        h = fmaf(wc4, Q.y - C.y, h);
        h = fmaf(wc5, Q.z - C.z, h);
        h = h >= 0.f ? h : NEG_SLOPE * h;
        vmax = fmaxf(vmax, h);
    }
    out[gp * 64 + c] = vmax;
}

extern "C" void kernel_launch(void* const* d_in, const int* in_sizes, int n_in,
                              void* d_out, int out_size, void* d_ws, size_t ws_size,
                              hipStream_t stream) {
    const float* pcd   = (const float*)d_in[0];
    const float* W     = (const float*)d_in[1];
    const float* bias  = (const float*)d_in[2];
    const float* gamma = (const float*)d_in[3];
    const float* beta  = (const float*)d_in[4];

    float* wsf = (float*)d_ws;
    float4* cloud   = (float4*)(wsf + FO_CLOUD);
    float* partials = wsf + FO_PART;
    float* part2    = wsf + FO_PART2;
    float* ab       = wsf + FO_AB;
    float* w2       = wsf + FO_W2;
    float* big      = wsf + FO_BIG;
    float* out      = (float*)d_out;

    const size_t need_fast = (size_t)FO_BIG * 4 + (size_t)P_TOT * 64 * 4 + 1024;
    const bool fast = ws_size >= need_fast;

    pack_kernel<<<P_TOT / 256, 256, 0, stream>>>(pcd, cloud);
    if (fast) {
        knn_kernel<true><<<NBLK, 512, 0, stream>>>(cloud, W, bias, partials, out, big, nullptr);
        finA_kernel<<<64, 128, 0, stream>>>(partials, part2);
        finB_kernel<<<1, 64, 0, stream>>>(part2, W, bias, gamma, beta, ab, w2);
        final_kernel<<<(P_TOT * 64) / 256, 256, 0, stream>>>(ab, big, out);
    } else {
        knn_kernel<false><<<NBLK, 512, 0, stream>>>(cloud, W, bias, partials, nullptr, nullptr, (int*)big);
        finA_kernel<<<64, 128, 0, stream>>>(partials, part2);
        finB_kernel<<<1, 64, 0, stream>>>(part2, W, bias, gamma, beta, ab, w2);
        out_kernel<<<P_TOT / 4, 256, 0, stream>>>(cloud, (int*)big, w2, out);
    }
}